// Round 11
// baseline (2203.990 us; speedup 1.0000x reference)
//
#include <hip/hip_runtime.h>

#define VV 32000
#define EE 256
#define HH 512
#define BB 32
#define SS 80
#define TT 80
// decoder rows = B*(T-1) = 2528, padded to 2560 (20 tiles of 128)

typedef __attribute__((ext_vector_type(8))) _Float16 half8;
typedef __attribute__((ext_vector_type(4))) _Float16 half4;
typedef __attribute__((ext_vector_type(4))) float floatx4;
typedef unsigned long long u64;

__device__ __forceinline__ void gload16(const _Float16* g, _Float16* l) {
  __builtin_amdgcn_global_load_lds((const __attribute__((address_space(1))) void*)g,
                                   (__attribute__((address_space(3))) void*)l, 16, 0, 0);
}

__device__ __forceinline__ float dot8(half8 a, half8 b, float c) {
  typedef __attribute__((ext_vector_type(2))) _Float16 half2v;
  half2v a0 = {a[0],a[1]}, a1 = {a[2],a[3]}, a2 = {a[4],a[5]}, a3 = {a[6],a[7]};
  half2v b0 = {b[0],b[1]}, b1 = {b[2],b[3]}, b2 = {b[4],b[5]}, b3 = {b[6],b[7]};
  c = __builtin_amdgcn_fdot2(a0, b0, c, false);
  c = __builtin_amdgcn_fdot2(a1, b1, c, false);
  c = __builtin_amdgcn_fdot2(a2, b2, c, false);
  c = __builtin_amdgcn_fdot2(a3, b3, c, false);
  return c;
}

__device__ __forceinline__ float sigm(float x) { return 1.f/(1.f + __expf(-x)); }
__device__ __forceinline__ float tanh_f(float x) { return 2.f/(1.f + __expf(-2.f*x)) - 1.f; }

// ---------------- embedding gather (fp32 -> fp16 rows) ----------------
__global__ __launch_bounds__(256) void embed_gather(
    const int* __restrict__ src, const int* __restrict__ tgt,
    const float* __restrict__ emb,
    _Float16* __restrict__ xsrc, _Float16* __restrict__ xdec)
{
  const int r = blockIdx.x;
  const int e = threadIdx.x; // EE == 256
  if (r < 2560) {
    const int tok = src[r];
    xsrc[(size_t)r*EE + e] = (_Float16)emb[(size_t)tok*EE + e];
  } else {
    const int rr = r - 2560;
    if (rr < 2528) {
      const int b = rr / 79, t = rr - b*79;
      const int tok = tgt[b*TT + t];
      xdec[(size_t)rr*EE + e] = (_Float16)emb[(size_t)tok*EE + e];
    } else {
      xdec[(size_t)rr*EE + e] = (_Float16)0.f;
    }
  }
}

// ---------------- weight fp32 -> fp16 conversion (Wih, out_W) ----------------
__global__ __launch_bounds__(256) void wconv(
    const float* __restrict__ we, const float* __restrict__ wd, const float* __restrict__ ow,
    _Float16* __restrict__ weh, _Float16* __restrict__ wdh, _Float16* __restrict__ owh)
{
  const long n1 = 1536L*256;
  const long total = 2*n1 + (long)VV*1024;
  for (long i = (long)blockIdx.x*256 + threadIdx.x; i < total; i += (long)gridDim.x*256) {
    if (i < n1)           weh[i]        = (_Float16)we[i];
    else if (i < 2*n1)    wdh[i-n1]     = (_Float16)wd[i-n1];
    else                  owh[i-2*n1]   = (_Float16)ow[i-2*n1];
  }
}

// ---------------- Whh fp32 -> tiled fp16 for step_k --------------------------
// Per WG w (0..31): j = (kt*4 + l4)*48 + g*16 + lr, entry = 8 halfs of
// W[(g*512 + w*16 + lr)][kt*32 + l4*8 .. +8].  out[w*3072 + j][8].
__global__ __launch_bounds__(128) void whh_tile(
    const float* __restrict__ We, const float* __restrict__ Wd,
    _Float16* __restrict__ oE, _Float16* __restrict__ oD)
{
  const int gid = blockIdx.x;           // 0..1535 = mat(2) x w(32) x blk(24)
  const int mat = gid / 768;
  const int rem = gid - mat*768;
  const int w = rem / 24, blk = rem - (rem/24)*24;
  const int j = blk*128 + threadIdx.x;  // 0..3071
  const int kt = j / 192;
  const int r2 = j - kt*192;
  const int l4 = r2 / 48;
  const int r  = r2 - l4*48;
  const int g = r >> 4, lr = r & 15;
  const float* W = mat ? Wd : We;
  _Float16* o = (mat ? oD : oE) + ((size_t)w*3072 + j)*8;
  const float* s = W + (size_t)(g*512 + w*16 + lr)*512 + kt*32 + l4*8;
#pragma unroll
  for (int e = 0; e < 8; ++e) o[e] = (_Float16)s[e];
}

// ---------------- generic fp16 MFMA GEMM: C(MxN) = A(MxK) * B(NxK)^T + bias ----
// MODE 0: C[row*ldc+col].
// MODE 1: logits scatter: row<2528 -> [b,t+1,:]; pad row 2528+b -> [b,0,:] = 0.
template<int MODE>
__global__ __launch_bounds__(256) void mfma_gemm(
    const _Float16* __restrict__ A, int lda,
    const _Float16* __restrict__ Bm, int ldb,
    const float* __restrict__ bias,
    float* __restrict__ Cout, int ldc, int K)
{
  __shared__ _Float16 As[4096];  // 128 x 32
  __shared__ _Float16 Bs[4096];  // 128 x 32
  const int tid = threadIdx.x;
  const int lane = tid & 63;
  const int wv = tid >> 6;
  const int wr = wv >> 1, wc = wv & 1;
  const int mt = blockIdx.y, nt = blockIdx.x;
  floatx4 acc[4][4];
#pragma unroll
  for (int i=0;i<4;++i)
#pragma unroll
    for (int j=0;j<4;++j) acc[i][j] = (floatx4){0.f,0.f,0.f,0.f};
  const int srow = lane >> 2;
  const int scol = (lane & 3) * 8;
  const _Float16* Ab = A + (size_t)(mt*128)*lda;
  const _Float16* Bb = Bm + (size_t)(nt*128)*ldb;
  const int g8 = (lane >> 4) * 8;
  const int lr = lane & 15;
  for (int kb = 0; kb < K; kb += 32) {
    __syncthreads();
#pragma unroll
    for (int cc = 0; cc < 2; ++cc) {
      const int c = wv*2 + cc;
      gload16(Ab + (size_t)(c*16 + srow)*lda + kb + scol, As + c*512);
      gload16(Bb + (size_t)(c*16 + srow)*ldb + kb + scol, Bs + c*512);
    }
    __syncthreads();
    half8 af[4], bf[4];
#pragma unroll
    for (int i=0;i<4;++i) af[i] = *(const half8*)(As + (wr*64 + i*16 + lr)*32 + g8);
#pragma unroll
    for (int j=0;j<4;++j) bf[j] = *(const half8*)(Bs + (wc*64 + j*16 + lr)*32 + g8);
#pragma unroll
    for (int i=0;i<4;++i)
#pragma unroll
      for (int j=0;j<4;++j)
        acc[i][j] = __builtin_amdgcn_mfma_f32_16x16x32_f16(af[i], bf[j], acc[i][j], 0,0,0);
  }
  const int rm = 4*(lane>>4);
#pragma unroll
  for (int i=0;i<4;++i) {
#pragma unroll
    for (int r=0;r<4;++r) {
      const int row = mt*128 + wr*64 + i*16 + rm + r;
#pragma unroll
      for (int j=0;j<4;++j) {
        const int col = nt*128 + wc*64 + j*16 + lr;
        const float v = acc[i][j][r] + bias[col];
        if (MODE == 0) {
          Cout[(size_t)row*ldc + col] = v;
        } else {
          if (row < 2528) {
            const int b = row / 79;
            const int t = row - b*79;
            Cout[(size_t)(b*80 + t + 1)*VV + col] = v;
          } else {
            Cout[(size_t)((row - 2528)*80)*VV + col] = 0.f;  // logits[b,0,:]=0
          }
        }
      }
    }
  }
}

// ---------------- attention body (device fn; 128 threads) --------------------
__device__ __forceinline__ void attn_body(
    char* smem, int b2, int trow,
    const _Float16* eoR, const _Float16* h16att, _Float16* comb)
{
  _Float16* hsh = (_Float16*)smem;      // [512]
  float* sc = (float*)(hsh + 512);      // [80]
  float* aw = sc + 80;                  // [80]
  const int tid = threadIdx.x, lane = tid & 63, wv = tid >> 6;
  ((u64*)hsh)[tid] = ((const u64*)h16att)[b2*128 + tid];
  __syncthreads();
  const half8 hf = *(const half8*)&hsh[lane*8];
  const _Float16* eob = eoR + (size_t)b2*SS*HH;
#pragma unroll 4
  for (int i = 0; i < 40; ++i) {
    const int s = wv*40 + i;
    const half8 ev = *(const half8*)&eob[(size_t)s*HH + lane*8];
    float pt = dot8(ev, hf, 0.f);
#pragma unroll
    for (int o = 32; o; o >>= 1) pt += __shfl_xor(pt, o);
    if (lane == 0) sc[s] = pt;
  }
  __syncthreads();
  if (wv == 0) {
    const float v0 = sc[lane];
    const float v1 = (lane < 16) ? sc[64+lane] : -1e30f;
    float m = fmaxf(v0, v1);
#pragma unroll
    for (int o = 32; o; o >>= 1) m = fmaxf(m, __shfl_xor(m, o));
    const float e0 = __expf(v0 - m);
    const float e1 = (lane < 16) ? __expf(v1 - m) : 0.f;
    float ssum = e0 + e1;
#pragma unroll
    for (int o = 32; o; o >>= 1) ssum += __shfl_xor(ssum, o);
    const float inv = 1.f/ssum;
    aw[lane] = e0*inv;
    if (lane < 16) aw[64+lane] = e1*inv;
  }
  __syncthreads();
  float c0=0.f, c1=0.f, c2=0.f, c3=0.f;
  const _Float16* ebase = eob + tid*4;
#pragma unroll 8
  for (int s = 0; s < SS; ++s) {
    const float a = aw[s];
    const half4 hv = *(const half4*)(ebase + (size_t)s*HH);
    c0 += a*(float)hv[0]; c1 += a*(float)hv[1];
    c2 += a*(float)hv[2]; c3 += a*(float)hv[3];
  }
  _Float16* cr = comb + ((size_t)b2*79 + trow)*1024;
  *(u64*)&cr[tid*4] = *(const u64*)&hsh[tid*4];
  union { u64 q; _Float16 h[4]; } cu;
  cu.h[0]=(_Float16)c0; cu.h[1]=(_Float16)c1; cu.h[2]=(_Float16)c2; cu.h[3]=(_Float16)c3;
  *(u64*)&cr[512 + tid*4] = cu.q;
}

// ---------------- one GRU timestep as its own kernel -------------------------
// WGs 0..31: GRU for all 32 batches (WG w owns h cols [w*16,w*16+16)).
// WGs 32..63 (decoder launches): attention(trow) from PREVIOUS kernel's h.
// Cross-kernel coherence via kernel boundaries: plain loads/stores only.
__global__ __launch_bounds__(128) void step_k(
    const _Float16* __restrict__ wT,    // tiled Whh fp16 [32][3072][8]
    const float* __restrict__ bhh,      // 1536
    const float* __restrict__ gi_t,     // gi + t*1536 (batch stride gstride)
    long gstride,
    const _Float16* __restrict__ h16r, _Float16* __restrict__ h16w,
    const float* __restrict__ h32r, float* __restrict__ h32w,
    _Float16* __restrict__ eoW, int eok,        // encoder: write eo row
    const _Float16* eoR,                        // att: eo base (or null)
    const _Float16* h16att,                     // att: h(trow) buffer
    _Float16* __restrict__ comb, int trow)
{
  extern __shared__ char smem[];
  const int tid = threadIdx.x;
  const int lane = tid & 63;
  const int wv = tid >> 6;

  if (blockIdx.x >= 32) {               // ---- attention WG ----
    if (eoR && trow >= 0) attn_body(smem, blockIdx.x - 32, trow, eoR, h16att, comb);
    return;
  }

  // ---- GRU WG ----
  const int w = blockIdx.x;
  const int lr = lane & 15;
  const int l4 = lane >> 4;
  const int b  = wv*16 + lr;
  const int jc = w*16 + 4*l4;
  _Float16* whh = (_Float16*)smem;      // [3072][8] = 48KB, j-linear

  // stage Whh slice (L2-warm after first step): 24 x gload16 per thread
  const _Float16* wsrc = wT + (size_t)w*3072*8;
#pragma unroll
  for (int i = 0; i < 24; ++i)
    gload16(wsrc + ((size_t)i*128 + wv*64 + lane)*8, whh + (i*128 + wv*64)*8);

  // h fragments (plain loads, pipelined)
  const u64* hr = (const u64*)h16r;
  u64 hq[32];
#pragma unroll
  for (int kt = 0; kt < 16; ++kt) {
    hq[2*kt]   = hr[b*128 + l4*2 + kt*8];
    hq[2*kt+1] = hr[b*128 + l4*2 + kt*8 + 1];
  }
  const float* girow = gi_t + (size_t)b*gstride;
  const floatx4 gr = *(const floatx4*)(girow + jc);
  const floatx4 gz = *(const floatx4*)(girow + HH + jc);
  const floatx4 gn = *(const floatx4*)(girow + 2*HH + jc);
  const floatx4 bR = *(const floatx4*)&bhh[jc];
  const floatx4 bZ = *(const floatx4*)&bhh[HH + jc];
  const floatx4 bN = *(const floatx4*)&bhh[2*HH + jc];
  const floatx4 hp = *(const floatx4*)&h32r[(size_t)b*HH + jc];

  __syncthreads();                      // staging complete (vmcnt drained)

  floatx4 a0 = (floatx4){0.f,0.f,0.f,0.f}, a1 = a0, a2 = a0;
#pragma unroll
  for (int kt = 0; kt < 16; ++kt) {
    union { u64 q[2]; half8 v; } hu;
    hu.q[0] = hq[2*kt]; hu.q[1] = hq[2*kt+1];
    const int jb = (kt*4 + l4)*48;
    const half8 x0 = *(const half8*)&whh[(jb + lr)*8];
    const half8 x1 = *(const half8*)&whh[(jb + 16 + lr)*8];
    const half8 x2 = *(const half8*)&whh[(jb + 32 + lr)*8];
    a0 = __builtin_amdgcn_mfma_f32_16x16x32_f16(x0, hu.v, a0, 0,0,0);
    a1 = __builtin_amdgcn_mfma_f32_16x16x32_f16(x1, hu.v, a1, 0,0,0);
    a2 = __builtin_amdgcn_mfma_f32_16x16x32_f16(x2, hu.v, a2, 0,0,0);
  }
  union { u64 q; _Float16 h[4]; } hw;
  floatx4 hn4;
#pragma unroll
  for (int r = 0; r < 4; ++r) {
    const float rg = sigm(gr[r] + a0[r] + bR[r]);
    const float zg = sigm(gz[r] + a1[r] + bZ[r]);
    const float ng = tanh_f(gn[r] + rg*(a2[r] + bN[r]));
    const float hn = (1.f - zg)*ng + zg*hp[r];
    hn4[r] = hn;
    hw.h[r] = (_Float16)hn;
  }
  ((u64*)h16w)[b*128 + w*4 + l4] = hw.q;
  *(floatx4*)&h32w[(size_t)b*HH + jc] = hn4;
  if (eoW) ((u64*)eoW)[((size_t)b*SS + eok)*128 + w*4 + l4] = hw.q;
}

// ---------------- final attention (t = 78) ----------------
__global__ __launch_bounds__(128) void att_last(
    const _Float16* eoR, const _Float16* h16att, _Float16* __restrict__ comb)
{
  extern __shared__ char smem[];
  attn_body(smem, blockIdx.x, TT-2, eoR, h16att, comb);
}

extern "C" void kernel_launch(void* const* d_in, const int* in_sizes, int n_in,
                              void* d_out, int out_size, void* d_ws, size_t ws_size,
                              hipStream_t stream) {
  (void)in_sizes; (void)n_in; (void)out_size; (void)ws_size;
  const int*   src  = (const int*)d_in[0];
  const int*   tgt  = (const int*)d_in[1];
  const float* emb  = (const float*)d_in[2];
  const float* eWih = (const float*)d_in[3];
  const float* eWhh = (const float*)d_in[4];
  const float* ebih = (const float*)d_in[5];
  const float* ebhh = (const float*)d_in[6];
  const float* dWih = (const float*)d_in[7];
  const float* dWhh = (const float*)d_in[8];
  const float* dbih = (const float*)d_in[9];
  const float* dbhh = (const float*)d_in[10];
  const float* outW = (const float*)d_in[11];
  const float* outb = (const float*)d_in[12];
  float* out = (float*)d_out;

  char* p = (char*)d_ws;
  auto alloc = [&](size_t n){ char* r = p; p += (n + 255) & ~(size_t)255; return r; };
  _Float16* xsrc = (_Float16*)alloc((size_t)2560*256*2);
  _Float16* xdec = (_Float16*)alloc((size_t)2560*256*2);
  _Float16* wEh  = (_Float16*)alloc((size_t)1536*256*2);
  _Float16* wDh  = (_Float16*)alloc((size_t)1536*256*2);
  _Float16* oWh  = (_Float16*)alloc((size_t)VV*1024*2);
  _Float16* wTe  = (_Float16*)alloc((size_t)32*3072*8*2);  // tiled enc Whh
  _Float16* wTd  = (_Float16*)alloc((size_t)32*3072*8*2);  // tiled dec Whh
  float*    giE  = (float*)alloc((size_t)2560*1536*4);
  float*    giD  = (float*)alloc((size_t)2560*1536*4);
  _Float16* h16a = (_Float16*)alloc((size_t)BB*HH*2);
  _Float16* h16b = (_Float16*)alloc((size_t)BB*HH*2);
  float*    h32a = (float*)alloc((size_t)BB*HH*4);
  float*    h32b = (float*)alloc((size_t)BB*HH*4);
  _Float16* eo   = (_Float16*)alloc((size_t)BB*SS*HH*2);
  _Float16* comb = (_Float16*)alloc((size_t)2560*1024*2);

  hipMemsetAsync(h16a, 0, (size_t)BB*HH*2, stream);
  hipMemsetAsync(h32a, 0, (size_t)BB*HH*4, stream);

  embed_gather<<<5120, 256, 0, stream>>>(src, tgt, emb, xsrc, xdec);
  wconv<<<2048, 256, 0, stream>>>(eWih, dWih, outW, wEh, wDh, oWh);
  whh_tile<<<1536, 128, 0, stream>>>(eWhh, dWhh, wTe, wTd);
  mfma_gemm<0><<<dim3(12,20), 256, 0, stream>>>(xsrc, 256, wEh, 256, ebih, giE, 1536, 256);
  mfma_gemm<0><<<dim3(12,20), 256, 0, stream>>>(xdec, 256, wDh, 256, dbih, giD, 1536, 256);

  const size_t SMEM = 49152;
  _Float16* h16s[2] = {h16a, h16b};
  float*    h32s[2] = {h32a, h32b};

  // encoder: k = 0..79. read buf k&1, write buf 1-(k&1).
  for (int k = 0; k < SS; ++k) {
    const int pr = k & 1, pw = 1 - pr;
    step_k<<<32, 128, SMEM, stream>>>(
        wTe, ebhh, giE + (size_t)k*1536, (long)SS*1536,
        h16s[pr], h16s[pw], h32s[pr], h32s[pw],
        eo, k, nullptr, nullptr, nullptr, -1);
  }
  // decoder: t = 0..78, k = 80+t; att WGs handle trow = t-1.
  for (int t = 0; t < TT-1; ++t) {
    const int k = 80 + t;
    const int pr = k & 1, pw = 1 - pr;
    step_k<<<64, 128, SMEM, stream>>>(
        wTd, dbhh, giD + (size_t)t*1536, (long)79*1536,
        h16s[pr], h16s[pw], h32s[pr], h32s[pw],
        nullptr, 0, (t >= 1) ? eo : nullptr, h16s[pr], comb, t - 1);
  }
  // final attention(78): h(78) was written by k=158 into buf 1-(158&1) = buf 1.
  att_last<<<32, 128, SMEM, stream>>>(eo, h16s[1], comb);

  // logits = comb @ oWh^T + outb (scatter; pad rows -> logits[b,0,:] = 0)
  mfma_gemm<1><<<dim3(250,20), 256, 0, stream>>>(comb, 1024, oWh, 1024, outb, out, 0, 1024);
}

// Round 12
// 1881.000 us; speedup vs baseline: 1.1717x; 1.1717x over previous
//
#include <hip/hip_runtime.h>

#define VV 32000
#define EE 256
#define HH 512
#define BB 32
#define SS 80
#define TT 80
// decoder rows = B*(T-1) = 2528, padded to 2560 (20 tiles of 128)

typedef __attribute__((ext_vector_type(8))) _Float16 half8;
typedef __attribute__((ext_vector_type(4))) _Float16 half4;
typedef __attribute__((ext_vector_type(4))) float floatx4;
typedef unsigned long long u64;

__device__ __forceinline__ void gload16(const _Float16* g, _Float16* l) {
  __builtin_amdgcn_global_load_lds((const __attribute__((address_space(1))) void*)g,
                                   (__attribute__((address_space(3))) void*)l, 16, 0, 0);
}

__device__ __forceinline__ u64 aload(const u64* p) {
  return __hip_atomic_load(p, __ATOMIC_RELAXED, __HIP_MEMORY_SCOPE_AGENT);
}
__device__ __forceinline__ void astore(u64* p, u64 v) {
  __hip_atomic_store(p, v, __ATOMIC_RELAXED, __HIP_MEMORY_SCOPE_AGENT);
}

__device__ __forceinline__ float dot8(half8 a, half8 b, float c) {
  typedef __attribute__((ext_vector_type(2))) _Float16 half2v;
  half2v a0 = {a[0],a[1]}, a1 = {a[2],a[3]}, a2 = {a[4],a[5]}, a3 = {a[6],a[7]};
  half2v b0 = {b[0],b[1]}, b1 = {b[2],b[3]}, b2 = {b[4],b[5]}, b3 = {b[6],b[7]};
  c = __builtin_amdgcn_fdot2(a0, b0, c, false);
  c = __builtin_amdgcn_fdot2(a1, b1, c, false);
  c = __builtin_amdgcn_fdot2(a2, b2, c, false);
  c = __builtin_amdgcn_fdot2(a3, b3, c, false);
  return c;
}

__device__ __forceinline__ float sigm(float x) { return 1.f/(1.f + __expf(-x)); }
__device__ __forceinline__ float tanh_f(float x) { return 2.f/(1.f + __expf(-2.f*x)) - 1.f; }

// ---------------- embedding gather (fp32 -> fp16 rows) ----------------
__global__ __launch_bounds__(256) void embed_gather(
    const int* __restrict__ src, const int* __restrict__ tgt,
    const float* __restrict__ emb,
    _Float16* __restrict__ xsrc, _Float16* __restrict__ xdec)
{
  const int r = blockIdx.x;
  const int e = threadIdx.x; // EE == 256
  if (r < 2560) {
    const int tok = src[r];
    xsrc[(size_t)r*EE + e] = (_Float16)emb[(size_t)tok*EE + e];
  } else {
    const int rr = r - 2560;
    if (rr < 2528) {
      const int b = rr / 79, t = rr - b*79;
      const int tok = tgt[b*TT + t];
      xdec[(size_t)rr*EE + e] = (_Float16)emb[(size_t)tok*EE + e];
    } else {
      xdec[(size_t)rr*EE + e] = (_Float16)0.f;
    }
  }
}

// ---------------- weight fp32 -> fp16 conversion (Wih, out_W) ----------------
__global__ __launch_bounds__(256) void wconv(
    const float* __restrict__ we, const float* __restrict__ wd, const float* __restrict__ ow,
    _Float16* __restrict__ weh, _Float16* __restrict__ wdh, _Float16* __restrict__ owh)
{
  const long n1 = 1536L*256;
  const long total = 2*n1 + (long)VV*1024;
  for (long i = (long)blockIdx.x*256 + threadIdx.x; i < total; i += (long)gridDim.x*256) {
    if (i < n1)           weh[i]        = (_Float16)we[i];
    else if (i < 2*n1)    wdh[i-n1]     = (_Float16)wd[i-n1];
    else                  owh[i-2*n1]   = (_Float16)ow[i-2*n1];
  }
}

// ---------------- fp16 MFMA GEMM (gi prep): C = A * B^T + bias --------------
__global__ __launch_bounds__(256) void mfma_gemm(
    const _Float16* __restrict__ A, int lda,
    const _Float16* __restrict__ Bm, int ldb,
    const float* __restrict__ bias,
    float* __restrict__ Cout, int ldc, int K)
{
  __shared__ _Float16 As[4096];  // 128 x 32
  __shared__ _Float16 Bs[4096];  // 128 x 32
  const int tid = threadIdx.x;
  const int lane = tid & 63;
  const int wv = tid >> 6;
  const int wr = wv >> 1, wc = wv & 1;
  const int mt = blockIdx.y, nt = blockIdx.x;
  floatx4 acc[4][4];
#pragma unroll
  for (int i=0;i<4;++i)
#pragma unroll
    for (int j=0;j<4;++j) acc[i][j] = (floatx4){0.f,0.f,0.f,0.f};
  const int srow = lane >> 2;
  const int scol = (lane & 3) * 8;
  const _Float16* Ab = A + (size_t)(mt*128)*lda;
  const _Float16* Bb = Bm + (size_t)(nt*128)*ldb;
  const int g8 = (lane >> 4) * 8;
  const int lr = lane & 15;
  for (int kb = 0; kb < K; kb += 32) {
    __syncthreads();
#pragma unroll
    for (int cc = 0; cc < 2; ++cc) {
      const int c = wv*2 + cc;
      gload16(Ab + (size_t)(c*16 + srow)*lda + kb + scol, As + c*512);
      gload16(Bb + (size_t)(c*16 + srow)*ldb + kb + scol, Bs + c*512);
    }
    __syncthreads();
    half8 af[4], bf[4];
#pragma unroll
    for (int i=0;i<4;++i) af[i] = *(const half8*)(As + (wr*64 + i*16 + lr)*32 + g8);
#pragma unroll
    for (int j=0;j<4;++j) bf[j] = *(const half8*)(Bs + (wc*64 + j*16 + lr)*32 + g8);
#pragma unroll
    for (int i=0;i<4;++i)
#pragma unroll
      for (int j=0;j<4;++j)
        acc[i][j] = __builtin_amdgcn_mfma_f32_16x16x32_f16(af[i], bf[j], acc[i][j], 0,0,0);
  }
  const int rm = 4*(lane>>4);
#pragma unroll
  for (int i=0;i<4;++i) {
#pragma unroll
    for (int r=0;r<4;++r) {
      const int row = mt*128 + wr*64 + i*16 + rm + r;
#pragma unroll
      for (int j=0;j<4;++j) {
        const int col = nt*128 + wc*64 + j*16 + lr;
        Cout[(size_t)row*ldc + col] = acc[i][j][r] + bias[col];
      }
    }
  }
}

// ---------------- logits GEMM, XCD-clustered tile order ----------------------
// grid 5120 x 256. p%8 ~ XCD (dispatch round-robin heuristic); nt = p%8 + 8*k
// so the 20 row-tiles sharing one 256KB B panel run consecutively on ONE XCD
// -> each B panel fetched from HBM once (64MB total vs 695MB measured in r11).
// Scatter: row<2528 -> out[b, t+1, :]; pad row 2528+b -> out[b, 0, :] = 0.
__global__ __launch_bounds__(256) void logits_gemm(
    const _Float16* __restrict__ A,     // comb [2560][1024]
    const _Float16* __restrict__ Bm,    // oWh  [32000][1024]
    const float* __restrict__ bias, float* __restrict__ out)
{
  const int p = blockIdx.x;
  const int x = p & 7, s = p >> 3;
  const int nt = x + 8*(s / 20);
  const int mt = s % 20;
  if (nt >= 250) return;
  __shared__ _Float16 As[4096];  // 128 x 32
  __shared__ _Float16 Bs[4096];  // 128 x 32
  const int tid = threadIdx.x;
  const int lane = tid & 63;
  const int wv = tid >> 6;
  const int wr = wv >> 1, wc = wv & 1;
  floatx4 acc[4][4];
#pragma unroll
  for (int i=0;i<4;++i)
#pragma unroll
    for (int j=0;j<4;++j) acc[i][j] = (floatx4){0.f,0.f,0.f,0.f};
  const int srow = lane >> 2;
  const int scol = (lane & 3) * 8;
  const _Float16* Ab = A + (size_t)(mt*128)*1024;
  const _Float16* Bb = Bm + (size_t)(nt*128)*1024;
  const int g8 = (lane >> 4) * 8;
  const int lr = lane & 15;
  for (int kb = 0; kb < 1024; kb += 32) {
    __syncthreads();
#pragma unroll
    for (int cc = 0; cc < 2; ++cc) {
      const int c = wv*2 + cc;
      gload16(Ab + (size_t)(c*16 + srow)*1024 + kb + scol, As + c*512);
      gload16(Bb + (size_t)(c*16 + srow)*1024 + kb + scol, Bs + c*512);
    }
    __syncthreads();
    half8 af[4], bf[4];
#pragma unroll
    for (int i=0;i<4;++i) af[i] = *(const half8*)(As + (wr*64 + i*16 + lr)*32 + g8);
#pragma unroll
    for (int j=0;j<4;++j) bf[j] = *(const half8*)(Bs + (wc*64 + j*16 + lr)*32 + g8);
#pragma unroll
    for (int i=0;i<4;++i)
#pragma unroll
      for (int j=0;j<4;++j)
        acc[i][j] = __builtin_amdgcn_mfma_f32_16x16x32_f16(af[i], bf[j], acc[i][j], 0,0,0);
  }
  const int rm = 4*(lane>>4);
#pragma unroll
  for (int i=0;i<4;++i) {
#pragma unroll
    for (int r=0;r<4;++r) {
      const int row = mt*128 + wr*64 + i*16 + rm + r;
#pragma unroll
      for (int j=0;j<4;++j) {
        const int col = nt*128 + wc*64 + j*16 + lr;
        if (row < 2528) {
          const int b = row / 79;
          const int t = row - b*79;
          out[(size_t)(b*80 + t + 1)*VV + col] = acc[i][j][r] + bias[col];
        } else {
          out[(size_t)((row - 2528)*80)*VV + col] = 0.f;   // logits[b,0,:] = 0
        }
      }
    }
  }
}

// ---------------- fused recurrence (r5-proven distributed flags) -------------
// 32 WGs x 128 threads. WG w owns h cols [w*16,w*16+16); Whh slice (48x512
// fp16) resident in LDS. Producer: sc1 data stores -> vmcnt(0) -> monotone
// step number to its OWN flag line. Consumer: 32 lanes poll the 32 producer
// flags, then burst-load h. Ping-pong depth 2. Decoder attention deferred one
// step so no WG waits on another's attention.
#define SEQ_SMEM ((48*520 + 80*512 + 512)*2 + 160*4)
__global__ __launch_bounds__(128) void seq_fused(
    const float* __restrict__ eWhh, const float* __restrict__ dWhh,
    const float* __restrict__ ebhh, const float* __restrict__ dbhh,
    const float* __restrict__ giE, const float* __restrict__ giD,
    _Float16* __restrict__ h16,    // ping-pong 2 x 32 x 512 fp16
    _Float16* __restrict__ comb,
    unsigned* __restrict__ flags)  // [2][32] monotone counters, 128B apart
{
  extern __shared__ char smem[];
  _Float16* whh  = (_Float16*)smem;        // [48][520] fp16 (padded rows)
  _Float16* eo_l = whh + 48*520;           // [80][512] fp16
  _Float16* hsh  = eo_l + 80*512;          // [512]
  float* sc = (float*)(hsh + 512);         // [80]
  float* aw = sc + 80;                     // [80]

  const int w = blockIdx.x;
  const int tid = threadIdx.x;
  const int lane = tid & 63;
  const int wv = tid >> 6;            // 0..1 batch group
  const int lr = lane & 15;
  const int l4 = lane >> 4;           // 0..3
  const int b  = wv*16 + lr;          // batch this thread covers
  const int jc = w*16 + 4*l4;         // global h-col base (4 wide)

  auto loadW = [&](const float* W){
    for (int i = tid; i < 48*512; i += 128) {
      const int r = i >> 9, k = i & 511;
      whh[r*520 + k] = (_Float16)W[((size_t)(r>>4)*512 + w*16 + (r&15))*512 + k];
    }
  };
  auto wait_flags = [&](int buf, unsigned tgt){
    if (tid < 32) {
      while (__hip_atomic_load(&flags[(buf*32 + tid)*32], __ATOMIC_RELAXED,
                               __HIP_MEMORY_SCOPE_AGENT) < tgt)
        __builtin_amdgcn_s_sleep(1);
    }
    __syncthreads();
  };
  auto publish = [&](int buf, unsigned val){
    asm volatile("s_waitcnt vmcnt(0)" ::: "memory");   // all sc1 data stores done
    __syncthreads();
    if (tid == 0)
      __hip_atomic_store(&flags[(buf*32 + w)*32], val, __ATOMIC_RELAXED,
                         __HIP_MEMORY_SCOPE_AGENT);
  };

  const floatx4 ebr = *(const floatx4*)&ebhh[jc];
  const floatx4 ebz = *(const floatx4*)&ebhh[HH + jc];
  const floatx4 ebn = *(const floatx4*)&ebhh[2*HH + jc];
  const floatx4 dbr = *(const floatx4*)&dbhh[jc];
  const floatx4 dbz = *(const floatx4*)&dbhh[HH + jc];
  const floatx4 dbn = *(const floatx4*)&dbhh[2*HH + jc];

  float hp[4] = {0.f, 0.f, 0.f, 0.f};   // fp32 h_prev (batch b, cols jc..jc+3)

  auto gru = [&](floatx4 gr, floatx4 gz, floatx4 gn,
                 floatx4 bR, floatx4 bZ, floatx4 bN,
                 const u64* bufR, u64* bufW, _Float16* stash){
    const u64* hb = bufR + b*128 + l4*2;
    u64 hq[32];
#pragma unroll
    for (int kt = 0; kt < 16; ++kt) {
      hq[2*kt]   = aload(hb + kt*8);
      hq[2*kt+1] = aload(hb + kt*8 + 1);
    }
    u64 sq = 0;
    if (stash) sq = aload(bufR + w*128 + tid);
    floatx4 a0 = (floatx4){0.f,0.f,0.f,0.f}, a1 = a0, a2 = a0;
#pragma unroll
    for (int kt = 0; kt < 16; ++kt) {
      union { u64 q[2]; half8 v; } hu;
      hu.q[0] = hq[2*kt]; hu.q[1] = hq[2*kt+1];
      const int ko = kt*32 + l4*8;
      const half8 x0 = *(const half8*)&whh[(     lr)*520 + ko];
      const half8 x1 = *(const half8*)&whh[(16 + lr)*520 + ko];
      const half8 x2 = *(const half8*)&whh[(32 + lr)*520 + ko];
      a0 = __builtin_amdgcn_mfma_f32_16x16x32_f16(x0, hu.v, a0, 0,0,0);
      a1 = __builtin_amdgcn_mfma_f32_16x16x32_f16(x1, hu.v, a1, 0,0,0);
      a2 = __builtin_amdgcn_mfma_f32_16x16x32_f16(x2, hu.v, a2, 0,0,0);
    }
    union { u64 q; _Float16 h[4]; } hw;
#pragma unroll
    for (int r = 0; r < 4; ++r) {
      const float rg = sigm(gr[r] + a0[r] + bR[r]);
      const float zg = sigm(gz[r] + a1[r] + bZ[r]);
      const float ng = tanh_f(gn[r] + rg*(a2[r] + bN[r]));
      const float hn = (1.f - zg)*ng + zg*hp[r];
      hp[r] = hn;
      hw.h[r] = (_Float16)hn;
    }
    astore(bufW + b*128 + w*4 + l4, hw.q);
    if (stash) *(u64*)&stash[tid*4] = sq;
  };

  auto attention = [&](int trow){
    const half8 hf = *(const half8*)&hsh[lane*8];
#pragma unroll 4
    for (int i = 0; i < 40; ++i) {
      const int s = wv*40 + i;
      const half8 ev = *(const half8*)&eo_l[s*512 + lane*8];
      float pt = dot8(ev, hf, 0.f);
#pragma unroll
      for (int o = 32; o; o >>= 1) pt += __shfl_xor(pt, o);
      if (lane == 0) sc[s] = pt;
    }
    __syncthreads();
    if (wv == 0) {
      const float v0 = sc[lane];
      const float v1 = (lane < 16) ? sc[64+lane] : -1e30f;
      float m = fmaxf(v0, v1);
#pragma unroll
      for (int o = 32; o; o >>= 1) m = fmaxf(m, __shfl_xor(m, o));
      const float e0 = __expf(v0 - m);
      const float e1 = (lane < 16) ? __expf(v1 - m) : 0.f;
      float ssum = e0 + e1;
#pragma unroll
      for (int o = 32; o; o >>= 1) ssum += __shfl_xor(ssum, o);
      const float inv = 1.f/ssum;
      aw[lane] = e0*inv;
      if (lane < 16) aw[64+lane] = e1*inv;
    }
    __syncthreads();
    float c0=0.f, c1=0.f, c2=0.f, c3=0.f;
#pragma unroll 8
    for (int s = 0; s < SS; ++s) {
      const float a = aw[s];
      const half4 hv = *(const half4*)&eo_l[s*512 + tid*4];
      c0 += a*(float)hv[0]; c1 += a*(float)hv[1];
      c2 += a*(float)hv[2]; c3 += a*(float)hv[3];
    }
    _Float16* cr = comb + ((size_t)w*79 + trow)*1024;
    *(u64*)&cr[tid*4] = *(const u64*)&hsh[tid*4];
    union { u64 q; _Float16 h[4]; } cu;
    cu.h[0]=(_Float16)c0; cu.h[1]=(_Float16)c1; cu.h[2]=(_Float16)c2; cu.h[3]=(_Float16)c3;
    *(u64*)&cr[512 + tid*4] = cu.q;
  };

  // init ping buffer 0 (own word), load enc weights, publish step 0
  astore((u64*)h16 + w*128 + tid, 0ull);
  loadW(eWhh);
  publish(0, 1);

  // -------- encoder: k = 0..79 --------
  for (int k = 0; k < SS; ++k) {
    const int p = k & 1;
    const float* girow = giE + (size_t)(b*SS + k)*1536 + jc;
    const floatx4 gr = *(const floatx4*)(girow);          // prefetch pre-wait
    const floatx4 gz = *(const floatx4*)(girow + HH);
    const floatx4 gn = *(const floatx4*)(girow + 2*HH);
    wait_flags(p, (unsigned)(k+1));
    gru(gr, gz, gn, ebr, ebz, ebn,
        (u64*)h16 + (size_t)p*(BB*HH/4), (u64*)h16 + (size_t)(1-p)*(BB*HH/4),
        (k > 0) ? (eo_l + (k-1)*512) : nullptr);
    publish(1-p, (unsigned)(k+2));
  }

  // -------- decoder: k = 80..158 (t = k-80) --------
  __syncthreads();
  loadW(dWhh);
  __syncthreads();
  for (int t = 0; t < TT-1; ++t) {
    const int k = 80 + t;
    const int p = k & 1;
    const float* girow = giD + (size_t)(b*79 + t)*1536 + jc;
    const floatx4 gr = *(const floatx4*)(girow);
    const floatx4 gz = *(const floatx4*)(girow + HH);
    const floatx4 gn = *(const floatx4*)(girow + 2*HH);
    wait_flags(p, (unsigned)(k+1));
    gru(gr, gz, gn, dbr, dbz, dbn,
        (u64*)h16 + (size_t)p*(BB*HH/4), (u64*)h16 + (size_t)(1-p)*(BB*HH/4),
        (t == 0) ? (eo_l + 79*512) : hsh);   // t=0: enc h(79); else h(t-1)
    publish(1-p, (unsigned)(k+2));
    if (t > 0) { __syncthreads(); attention(t-1); }
  }
  // final: attention(78) on h(158) (buffer 1, flag val 160)
  wait_flags(1, 160u);
  {
    const u64 q = aload((const u64*)h16 + (size_t)1*(BB*HH/4) + w*128 + tid);
    *(u64*)&hsh[tid*4] = q;
  }
  __syncthreads();
  attention(TT-2);
}

extern "C" void kernel_launch(void* const* d_in, const int* in_sizes, int n_in,
                              void* d_out, int out_size, void* d_ws, size_t ws_size,
                              hipStream_t stream) {
  (void)in_sizes; (void)n_in; (void)out_size; (void)ws_size;
  const int*   src  = (const int*)d_in[0];
  const int*   tgt  = (const int*)d_in[1];
  const float* emb  = (const float*)d_in[2];
  const float* eWih = (const float*)d_in[3];
  const float* eWhh = (const float*)d_in[4];
  const float* ebih = (const float*)d_in[5];
  const float* ebhh = (const float*)d_in[6];
  const float* dWih = (const float*)d_in[7];
  const float* dWhh = (const float*)d_in[8];
  const float* dbih = (const float*)d_in[9];
  const float* dbhh = (const float*)d_in[10];
  const float* outW = (const float*)d_in[11];
  const float* outb = (const float*)d_in[12];
  float* out = (float*)d_out;

  char* p = (char*)d_ws;
  auto alloc = [&](size_t n){ char* r = p; p += (n + 255) & ~(size_t)255; return r; };
  _Float16* xsrc = (_Float16*)alloc((size_t)2560*256*2);
  _Float16* xdec = (_Float16*)alloc((size_t)2560*256*2);
  _Float16* wEh  = (_Float16*)alloc((size_t)1536*256*2);
  _Float16* wDh  = (_Float16*)alloc((size_t)1536*256*2);
  _Float16* oWh  = (_Float16*)alloc((size_t)VV*1024*2);
  float*    giE  = (float*)alloc((size_t)2560*1536*4);
  float*    giD  = (float*)alloc((size_t)2560*1536*4);
  _Float16* h16  = (_Float16*)alloc((size_t)2*BB*HH*2);   // ping-pong
  _Float16* comb = (_Float16*)alloc((size_t)2560*1024*2);
  unsigned* flags= (unsigned*)alloc(2*32*128);

  hipMemsetAsync(flags, 0, 2*32*128, stream);
  embed_gather<<<5120, 256, 0, stream>>>(src, tgt, emb, xsrc, xdec);
  wconv<<<2048, 256, 0, stream>>>(eWih, dWih, outW, wEh, wDh, oWh);
  mfma_gemm<<<dim3(12,20), 256, 0, stream>>>(xsrc, 256, wEh, 256, ebih, giE, 1536, 256);
  mfma_gemm<<<dim3(12,20), 256, 0, stream>>>(xdec, 256, wDh, 256, dbih, giD, 1536, 256);
  hipFuncSetAttribute((const void*)seq_fused,
                      hipFuncAttributeMaxDynamicSharedMemorySize, SEQ_SMEM);
  seq_fused<<<32, 128, SEQ_SMEM, stream>>>(eWhh, dWhh, ebhh, dbhh, giE, giD,
                                           h16, comb, flags);
  logits_gemm<<<5120, 256, 0, stream>>>(comb, oWh, outb, out);
}